// Round 2
// baseline (469.350 us; speedup 1.0000x reference)
//
#include <hip/hip_runtime.h>
#include <stdint.h>

typedef unsigned short u16;
typedef __attribute__((ext_vector_type(8))) _Float16 h8;  // 8 x fp16 (4 VGPRs)
typedef __attribute__((ext_vector_type(4))) float f4;     // 4 x f32 accumulator

#define B_ 2
#define SQ_ 2048
#define SK_ 2048
#define D_ 1024
#define H_ 16
#define DK_ 64

__device__ __forceinline__ u16 f2h(float f) {             // fp32 -> fp16 RNE
  union { _Float16 h; u16 u; } v; v.h = (_Float16)f; return v.u;
}
__device__ __forceinline__ float h2f(u16 b) {
  union { u16 u; _Float16 h; } v; v.u = b; return (float)v.h;
}

typedef const void __attribute__((address_space(1)))* gas1;
typedef void __attribute__((address_space(3)))* las3;
__device__ __forceinline__ void gld16(const void* g, void* l) {
  // async global->LDS, 16B per lane; LDS dest = wave-uniform base + lane*16
  __builtin_amdgcn_global_load_lds((gas1)g, (las3)l, 16, 0, 0);
}

// ---------------------------------------------------------------- casts
__global__ void rma_cast_x(const float* __restrict__ q, const float* __restrict__ v,
                           const float* __restrict__ r, u16* __restrict__ xq,
                           u16* __restrict__ xv, u16* __restrict__ xr) {
  const float* src = blockIdx.z == 0 ? q : (blockIdx.z == 1 ? v : r);
  u16* dst = blockIdx.z == 0 ? xq : (blockIdx.z == 1 ? xv : xr);
  int i = (blockIdx.x * 256 + threadIdx.x) * 8;
  float4 a = *(const float4*)(src + i);
  float4 b = *(const float4*)(src + i + 4);
  alignas(16) u16 t[8] = {f2h(a.x), f2h(a.y), f2h(a.z), f2h(a.w),
                          f2h(b.x), f2h(b.y), f2h(b.z), f2h(b.w)};
  *(int4*)(dst + i) = *(int4*)t;
}

__global__ void rma_cast_w(const float* __restrict__ w0, const float* __restrict__ w1,
                           const float* __restrict__ w2, const float* __restrict__ w3,
                           u16* __restrict__ o0, u16* __restrict__ o1,
                           u16* __restrict__ o2, u16* __restrict__ o3) {
  const float* src = blockIdx.z == 0 ? w0 : (blockIdx.z == 1 ? w1 : (blockIdx.z == 2 ? w2 : w3));
  u16* dst = blockIdx.z == 0 ? o0 : (blockIdx.z == 1 ? o1 : (blockIdx.z == 2 ? o2 : o3));
  int i = (blockIdx.x * 256 + threadIdx.x) * 8;
  float4 a = *(const float4*)(src + i);
  float4 b = *(const float4*)(src + i + 4);
  alignas(16) u16 t[8] = {f2h(a.x), f2h(a.y), f2h(a.z), f2h(a.w),
                          f2h(b.x), f2h(b.y), f2h(b.z), f2h(b.w)};
  *(int4*)(dst + i) = *(int4*)t;
}

// ---------------------------------------------------------------- GEMM core
// C[i][j] = sum_k A[i,k]*Bw[j,k]  (NT layout, fp16). 128x128 tile, BK=32, 256 thr.
__device__ __forceinline__ void gemm_mainloop(
    const u16* __restrict__ A, const u16* __restrict__ Bw, int K,
    u16* As, u16* Bs, int m0, int n0, f4 (&acc)[4][4]) {
  const int tid = threadIdx.x;
  const int w = tid >> 6, lane = tid & 63;
  const int quad = lane >> 4, ln = lane & 15;
  const int wm = (w >> 1) * 64, wn = (w & 1) * 64;
  const int c0 = tid, c1 = tid + 256;   // 16B chunk ids; row=c>>2, k8=(c&3)*8
  const u16* a0 = A + (size_t)(m0 + (c0 >> 2)) * K + (c0 & 3) * 8;
  const u16* a1 = A + (size_t)(m0 + (c1 >> 2)) * K + (c1 & 3) * 8;
  const u16* b0 = Bw + (size_t)(n0 + (c0 >> 2)) * K + (c0 & 3) * 8;
  const u16* b1 = Bw + (size_t)(n0 + (c1 >> 2)) * K + (c1 & 3) * 8;
  u16* As0 = As + (0 + w * 64) * 8;     // wave-uniform LDS bases
  u16* As1 = As + (256 + w * 64) * 8;
  u16* Bs0 = Bs + (0 + w * 64) * 8;
  u16* Bs1 = Bs + (256 + w * 64) * 8;
  for (int kt = 0; kt < K; kt += 32) {
    gld16(a0 + kt, As0);
    gld16(a1 + kt, As1);
    gld16(b0 + kt, Bs0);
    gld16(b1 + kt, Bs1);
    __syncthreads();
    h8 af[4], bf[4];
#pragma unroll
    for (int i = 0; i < 4; i++)
      af[i] = *(const h8*)&As[(wm + i * 16 + ln) * 32 + quad * 8];
#pragma unroll
    for (int i = 0; i < 4; i++)
      bf[i] = *(const h8*)&Bs[(wn + i * 16 + ln) * 32 + quad * 8];
#pragma unroll
    for (int i = 0; i < 4; i++)
#pragma unroll
      for (int j = 0; j < 4; j++)
        acc[i][j] = __builtin_amdgcn_mfma_f32_16x16x32_f16(af[i], bf[j], acc[i][j], 0, 0, 0);
    __syncthreads();
  }
}

// fused Q/V/R projections; z selects operand set + epilogue layout
__global__ __launch_bounds__(256, 2)
void rma_proj_gemm(const u16* __restrict__ Xq, const u16* __restrict__ Xv,
                   const u16* __restrict__ Xr, const u16* __restrict__ Wq,
                   const u16* __restrict__ Wv, const u16* __restrict__ Wr,
                   const float* __restrict__ bq, const float* __restrict__ bv,
                   const float* __restrict__ br, u16* __restrict__ Qb,
                   u16* __restrict__ Vb, float* __restrict__ Rp) {
  const int z = blockIdx.z;
  const u16* A = z == 0 ? Xq : (z == 1 ? Xv : Xr);
  const u16* Bw = z == 0 ? Wq : (z == 1 ? Wv : Wr);
  const float* bias = z == 0 ? bq : (z == 1 ? bv : br);
  __shared__ u16 As[128 * 32];
  __shared__ u16 Bs[128 * 32];
  const int m0 = blockIdx.x * 128, n0 = blockIdx.y * 128;
  f4 acc[4][4] = {};
  gemm_mainloop(A, Bw, D_, As, Bs, m0, n0, acc);
  const int tid = threadIdx.x;
  const int w = tid >> 6, lane = tid & 63;
  const int quad = lane >> 4, ln = lane & 15;
  const int wm = (w >> 1) * 64, wn = (w & 1) * 64;
#pragma unroll
  for (int i = 0; i < 4; i++)
#pragma unroll
    for (int j = 0; j < 4; j++) {
      const int colg = n0 + wn + j * 16 + ln;
      const float bb = bias[colg];
      const int h = colg >> 6, d = colg & 63;
#pragma unroll
      for (int r = 0; r < 4; r++) {
        const int rowg = m0 + wm + i * 16 + quad * 4 + r;
        const int b = rowg >> 11, s = rowg & 2047;
        const float v = acc[i][j][r] + bb;
        const size_t idx = ((size_t)(b * H_ + h) * SK_ + s) * DK_ + d;  // (B,H,S,DK)
        if (z == 2) Rp[idx] = v;
        else if (z == 1) Vb[idx] = f2h(v);
        else Qb[idx] = f2h(v);
      }
    }
}

__global__ __launch_bounds__(256, 2)
void rma_final_gemm(const u16* __restrict__ Og, const u16* __restrict__ Wo,
                    const float* __restrict__ bo, float* __restrict__ out) {
  __shared__ u16 As[128 * 32];
  __shared__ u16 Bs[128 * 32];
  const int m0 = blockIdx.x * 128, n0 = blockIdx.y * 128;
  f4 acc[4][4] = {};
  gemm_mainloop(Og, Wo, D_, As, Bs, m0, n0, acc);
  const int tid = threadIdx.x;
  const int w = tid >> 6, lane = tid & 63;
  const int quad = lane >> 4, ln = lane & 15;
  const int wm = (w >> 1) * 64, wn = (w & 1) * 64;
#pragma unroll
  for (int i = 0; i < 4; i++)
#pragma unroll
    for (int j = 0; j < 4; j++) {
      const int colg = n0 + wn + j * 16 + ln;
      const float bb = bo[colg];
#pragma unroll
      for (int r = 0; r < 4; r++) {
        const int rowg = m0 + wm + i * 16 + quad * 4 + r;
        out[(size_t)rowg * D_ + colg] = acc[i][j][r] + bb;
      }
    }
}

// ---------------------------------------------------------------- V transpose
// Vb (BH,S,DK) fp16 -> Vt (BH,DK,S) fp16, 64x64 LDS tiles
__global__ void rma_transpose_v(const u16* __restrict__ Vb, u16* __restrict__ Vt) {
  __shared__ u16 T[64 * 72];
  const int bh = blockIdx.y;
  const int s0 = blockIdx.x * 64;
  const int tid = threadIdx.x;
  const u16* src = Vb + ((size_t)bh * SK_ + s0) * DK_;
#pragma unroll
  for (int i = 0; i < 2; i++) {
    int c = tid + i * 256;
    int s = c >> 3, d8 = (c & 7) * 8;
    *(int4*)&T[s * 72 + d8] = *(const int4*)&src[(size_t)s * DK_ + d8];
  }
  __syncthreads();
  u16* dst = Vt + (size_t)bh * DK_ * SK_ + s0;
#pragma unroll
  for (int i = 0; i < 2; i++) {
    int c = tid + i * 256;
    int d = c >> 3, s8 = (c & 7) * 8;
    alignas(16) u16 tmp[8];
#pragma unroll
    for (int j = 0; j < 8; j++) tmp[j] = T[(s8 + j) * 72 + d];
    *(int4*)&dst[(size_t)d * SK_ + s8] = *(int4*)tmp;
  }
}

// ---------------------------------------------------------------- recurrence
// h_t = tanh(h_{t-1}*wsum + r_t), per (b,h,d) channel; wsum = sum_k W_h[h,d,k]
__global__ void rma_recurrence(const float* __restrict__ Rp, const float* __restrict__ Wh,
                               u16* __restrict__ Hst) {
  const int idx = blockIdx.x * 64 + threadIdx.x;   // 0..2047
  const int d = idx & 63, h = (idx >> 6) & 15, b = idx >> 10;
  const float* wr = Wh + (h * 64 + d) * 64;
  float ws = 0.f;
#pragma unroll 8
  for (int k = 0; k < 64; k++) ws += wr[k];
  const float C2 = 2.885390081777927f;  // 2*log2(e): tanh(y)=1-2/(2^(C2*y)+1)
  const float wc = ws * C2;
  const size_t base = (size_t)(b * H_ + h) * SK_ * DK_ + d;
  const float* r = Rp + base;
  u16* o = Hst + base;
  float hs = 0.f;
  for (int t = 0; t < SK_; t++) {
    float rc = r[(size_t)t * DK_] * C2;           // off-chain load+mul
    float x = __builtin_fmaf(hs, wc, rc);
    float e = exp2f(x);                           // v_exp_f32
    float inv = __builtin_amdgcn_rcpf(e + 1.0f);  // v_rcp_f32
    hs = __builtin_fmaf(-2.0f, inv, 1.0f);
    o[(size_t)t * DK_] = f2h(hs);
  }
}

// ---------------------------------------------------------------- flash attention
// per block: (b,h), 128 q-rows; loop 64-wide k-tiles with online softmax.
__global__ __launch_bounds__(256, 2)
void rma_flash(const u16* __restrict__ Qb, const u16* __restrict__ Hst,
               const u16* __restrict__ Vt, u16* __restrict__ Og) {
  __shared__ u16 Kt[64 * 72];    // [k_local][dk], stride 72
  __shared__ u16 Vts[64 * 72];   // [dk][k_local], stride 72
  __shared__ u16 Ps[128 * 72];   // [q_local][k_local], stride 72
  const int tid = threadIdx.x;
  const int w = tid >> 6, lane = tid & 63;
  const int quad = lane >> 4, ln = lane & 15;
  const int bh = blockIdx.y;
  const int q0 = blockIdx.x * 128;
  const float scale2 = 0.18033688011112042f;  // log2(e)/sqrt(DK)
  const u16* Qg = Qb + ((size_t)bh * SQ_ + q0) * DK_;
  const u16* Kg = Hst + (size_t)bh * SK_ * DK_;
  const u16* Vg = Vt + (size_t)bh * DK_ * SK_;
  h8 qf[2][2];
#pragma unroll
  for (int mt = 0; mt < 2; mt++)
#pragma unroll
    for (int ks = 0; ks < 2; ks++)
      qf[mt][ks] = *(const h8*)&Qg[(w * 32 + mt * 16 + ln) * DK_ + ks * 32 + quad * 8];
  f4 o[2][4] = {};
  float mst[2][4], lst[2][4];
#pragma unroll
  for (int mt = 0; mt < 2; mt++)
#pragma unroll
    for (int r = 0; r < 4; r++) { mst[mt][r] = -3e38f; lst[mt][r] = 0.f; }

  for (int kt = 0; kt < SK_; kt += 64) {
    // stage K-tile (Hst rows) and Vt-tile
#pragma unroll
    for (int i = 0; i < 2; i++) {
      int c = tid + i * 256;
      int rr = c >> 3, k8 = (c & 7) * 8;
      *(int4*)&Kt[rr * 72 + k8] = *(const int4*)&Kg[(size_t)(kt + rr) * DK_ + k8];
    }
#pragma unroll
    for (int i = 0; i < 2; i++) {
      int c = tid + i * 256;
      int dd = c >> 3, s8 = (c & 7) * 8;
      *(int4*)&Vts[dd * 72 + s8] = *(const int4*)&Vg[(size_t)dd * SK_ + kt + s8];
    }
    __syncthreads();
    // S = Q*K^T (scaled into log2 domain)
    f4 s[2][4];
#pragma unroll
    for (int nt = 0; nt < 4; nt++) {
      h8 b0 = *(const h8*)&Kt[(nt * 16 + ln) * 72 + quad * 8];
      h8 b1 = *(const h8*)&Kt[(nt * 16 + ln) * 72 + 32 + quad * 8];
#pragma unroll
      for (int mt = 0; mt < 2; mt++) {
        f4 t = {0.f, 0.f, 0.f, 0.f};
        t = __builtin_amdgcn_mfma_f32_16x16x32_f16(qf[mt][0], b0, t, 0, 0, 0);
        t = __builtin_amdgcn_mfma_f32_16x16x32_f16(qf[mt][1], b1, t, 0, 0, 0);
        s[mt][nt] = t * scale2;
      }
    }
    // online softmax (rows live entirely within the wave's 16-lane groups)
#pragma unroll
    for (int mt = 0; mt < 2; mt++) {
      float rmax[4], rsum[4], alpha[4];
#pragma unroll
      for (int r = 0; r < 4; r++) {
        float v = s[mt][0][r];
#pragma unroll
        for (int nt = 1; nt < 4; nt++) v = fmaxf(v, s[mt][nt][r]);
        rmax[r] = v;
      }
#pragma unroll
      for (int off = 1; off < 16; off <<= 1)
#pragma unroll
        for (int r = 0; r < 4; r++)
          rmax[r] = fmaxf(rmax[r], __shfl_xor(rmax[r], off, 64));
#pragma unroll
      for (int r = 0; r < 4; r++) {
        const float mnew = fmaxf(mst[mt][r], rmax[r]);
        alpha[r] = exp2f(mst[mt][r] - mnew);
        mst[mt][r] = mnew;
        float sum = 0.f;
        const int prow = (w * 32 + mt * 16 + quad * 4 + r) * 72 + ln;
#pragma unroll
        for (int nt = 0; nt < 4; nt++) {
          float p = exp2f(s[mt][nt][r] - mnew);
          u16 pv = f2h(p);
          Ps[prow + nt * 16] = pv;
          sum += h2f(pv);  // accumulate the value PV will actually use
        }
        rsum[r] = sum;
      }
#pragma unroll
      for (int off = 1; off < 16; off <<= 1)
#pragma unroll
        for (int r = 0; r < 4; r++) rsum[r] += __shfl_xor(rsum[r], off, 64);
#pragma unroll
      for (int r = 0; r < 4; r++) {
        lst[mt][r] = lst[mt][r] * alpha[r] + rsum[r];
#pragma unroll
        for (int dt = 0; dt < 4; dt++) o[mt][dt][r] *= alpha[r];
      }
    }
    __syncthreads();
    // O += P * V
#pragma unroll
    for (int ks = 0; ks < 2; ks++) {
      h8 a0 = *(const h8*)&Ps[(w * 32 + 0 + ln) * 72 + ks * 32 + quad * 8];
      h8 a1 = *(const h8*)&Ps[(w * 32 + 16 + ln) * 72 + ks * 32 + quad * 8];
#pragma unroll
      for (int dt = 0; dt < 4; dt++) {
        h8 bv = *(const h8*)&Vts[(dt * 16 + ln) * 72 + ks * 32 + quad * 8];
        o[0][dt] = __builtin_amdgcn_mfma_f32_16x16x32_f16(a0, bv, o[0][dt], 0, 0, 0);
        o[1][dt] = __builtin_amdgcn_mfma_f32_16x16x32_f16(a1, bv, o[1][dt], 0, 0, 0);
      }
    }
    __syncthreads();
  }
  // epilogue: O/l -> Og[b][q][h*64+d] (i.e. (B,SQ,D))
  const int b = bh >> 4, h = bh & 15;
#pragma unroll
  for (int mt = 0; mt < 2; mt++)
#pragma unroll
    for (int dt = 0; dt < 4; dt++)
#pragma unroll
      for (int r = 0; r < 4; r++) {
        const int q = q0 + w * 32 + mt * 16 + quad * 4 + r;
        const int d = dt * 16 + ln;
        const float v = o[mt][dt][r] / lst[mt][r];
        Og[((size_t)b * SQ_ + q) * D_ + h * DK_ + d] = f2h(v);
      }
}

// ---------------------------------------------------------------- launch
extern "C" void kernel_launch(void* const* d_in, const int* in_sizes, int n_in,
                              void* d_out, int out_size, void* d_ws, size_t ws_size,
                              hipStream_t stream) {
  const float* query = (const float*)d_in[0];
  // d_in[1] = key : unused by the reference forward
  const float* value = (const float*)d_in[2];
  const float* R = (const float*)d_in[3];
  const float* Wq = (const float*)d_in[4];
  const float* bq = (const float*)d_in[5];
  const float* Wv = (const float*)d_in[6];
  const float* bv = (const float*)d_in[7];
  const float* Wr = (const float*)d_in[8];
  const float* br = (const float*)d_in[9];
  const float* W_h = (const float*)d_in[10];
  const float* Wo = (const float*)d_in[11];
  const float* bo = (const float*)d_in[12];
  float* out = (float*)d_out;

  char* ws = (char*)d_ws;
  const size_t MB = 1 << 20;
  u16* Xq = (u16*)(ws + 0 * MB);    // 8MB fp16 query
  u16* Xv = (u16*)(ws + 8 * MB);    // 8MB fp16 value
  u16* Xr = (u16*)(ws + 16 * MB);   // 8MB fp16 R
  u16* Wqb = (u16*)(ws + 24 * MB);  // 2MB
  u16* Wvb = (u16*)(ws + 26 * MB);  // 2MB
  u16* Wrb = (u16*)(ws + 28 * MB);  // 2MB
  u16* Wob = (u16*)(ws + 30 * MB);  // 2MB
  u16* Qb = (u16*)(ws + 32 * MB);   // 8MB fp16 (B,H,SQ,DK)
  u16* Vb = (u16*)(ws + 40 * MB);   // 8MB fp16 (B,H,SK,DK)
  u16* Vt = (u16*)(ws + 48 * MB);   // 8MB fp16 (B,H,DK,SK)
  float* Rp = (float*)(ws + 56 * MB); // 16MB f32 (B,H,SK,DK)
  u16* Hs = (u16*)(ws + 72 * MB);   // 8MB fp16 (B,H,SK,DK)
  u16* Og = (u16*)(ws + 80 * MB);   // 8MB fp16 (B,SQ,D)  -> total 88MB

  rma_cast_x<<<dim3(2048, 1, 3), 256, 0, stream>>>(query, value, R, Xq, Xv, Xr);
  rma_cast_w<<<dim3(512, 1, 4), 256, 0, stream>>>(Wq, Wv, Wr, Wo, Wqb, Wvb, Wrb, Wob);
  rma_proj_gemm<<<dim3(32, 8, 3), 256, 0, stream>>>(Xq, Xv, Xr, Wqb, Wvb, Wrb,
                                                    bq, bv, br, Qb, Vb, Rp);
  rma_transpose_v<<<dim3(32, 32), 256, 0, stream>>>(Vb, Vt);
  rma_recurrence<<<dim3(32), 64, 0, stream>>>(Rp, W_h, Hs);
  rma_flash<<<dim3(16, 32), 256, 0, stream>>>(Qb, Hs, Vt, Og);
  rma_final_gemm<<<dim3(32, 8), 256, 0, stream>>>(Og, Wob, bo, out);
}